// Round 12
// baseline (908.974 us; speedup 1.0000x reference)
//
#include <hip/hip_runtime.h>
#include <math.h>

typedef unsigned long long u64;
typedef unsigned int u32;

// ---------------- retrieve_key: [256] queries vs [15] keys over L=150528 ----
#define L_TOT  150528
#define ROW4   37632      // L_TOT/4 float4 per row
#define NCHUNK 7
#define CH4    5376       // ROW4/NCHUNK
#define R_ITERS 84        // CH4/64
#define NBT    32         // b-tiles of 8
#define BTILE  8
#define NCLS   15

// ---------------- FPS ------------------------------------------------------
#define N_E    12544
#define DIM    768
#define NBLK   256
#define PPB    49         // points per block (256*49 = 12544, exact)
#define NSAMP  196
#define EPB    (PPB*DIM)  // 37632 floats = 150528 B in LDS
#define RSTRIDE 16        // u64 stride between result replicas (128 B)

__device__ __forceinline__ float wave_sum(float v) {
#pragma unroll
  for (int m = 1; m < 64; m <<= 1) v += __shfl_xor(v, m, 64);
  return v;
}

__device__ __forceinline__ u64 wave_max_u64(u64 v) {
#pragma unroll
  for (int m = 1; m < 64; m <<= 1) {
    u64 o = __shfl_xor(v, m, 64);
    if (o > v) v = o;
  }
  return v;
}

__device__ __forceinline__ u64 key_from_word(u64 w) {
  return (((w >> 16) & 0xffffffffull) << 32) |
         (u64)(u32)(~(u32)(w & 0xffffull));
}

__device__ __forceinline__ u64 word_from_key(u64 s, u64 k) {
  const u32 bidx = ~(u32)(k & 0xffffffffull);
  const u32 bdist = (u32)(k >> 32);
  return (s << 48) | ((u64)bdist << 16) | (u64)bidx;
}

// Partial dot products: grid (32 b-tiles, 7 L-chunks), block 256.
__global__ __launch_bounds__(256) void retrieve_partial(
    const float* __restrict__ q, const float* __restrict__ k,
    float* __restrict__ part, float* __restrict__ kkpart) {
  const int bt = blockIdx.x;     // 0..31
  const int lc = blockIdx.y;     // 0..6
  const int tid = threadIdx.x;
  const int w = tid >> 6, lane = tid & 63;
  const int cbase = w * 4;
  const int ccnt = (w == 3) ? 3 : 4;
  const float4* qf = (const float4*)q;
  const float4* kf = (const float4*)k;
  const int fbase = lc * CH4 + lane;

  float acc[BTILE][4];
  float qq[BTILE];
  float kkv[4];
#pragma unroll
  for (int b = 0; b < BTILE; ++b) {
    qq[b] = 0.f;
#pragma unroll
    for (int c = 0; c < 4; ++c) acc[b][c] = 0.f;
  }
#pragma unroll
  for (int c = 0; c < 4; ++c) kkv[c] = 0.f;

  for (int it = 0; it < R_ITERS; ++it) {
    const int f = fbase + it * 64;
    float4 kv[4];
#pragma unroll
    for (int c = 0; c < 4; ++c)
      if (c < ccnt) kv[c] = kf[(size_t)(cbase + c) * ROW4 + f];
    if (bt == 0) {
#pragma unroll
      for (int c = 0; c < 4; ++c)
        if (c < ccnt)
          kkv[c] += kv[c].x*kv[c].x + kv[c].y*kv[c].y + kv[c].z*kv[c].z + kv[c].w*kv[c].w;
    }
#pragma unroll
    for (int b = 0; b < BTILE; ++b) {
      float4 qv = qf[(size_t)(bt * BTILE + b) * ROW4 + f];
#pragma unroll
      for (int c = 0; c < 4; ++c)
        if (c < ccnt)
          acc[b][c] += qv.x*kv[c].x + qv.y*kv[c].y + qv.z*kv[c].z + qv.w*kv[c].w;
      if (w == 3)
        qq[b] += qv.x*qv.x + qv.y*qv.y + qv.z*qv.z + qv.w*qv.w;
    }
  }

  const size_t pb = (size_t)(lc * NBT + bt) * 16;
#pragma unroll
  for (int b = 0; b < BTILE; ++b) {
#pragma unroll
    for (int c = 0; c < 4; ++c) {
      float v = wave_sum(acc[b][c]);
      if (lane == 0 && c < ccnt) part[(pb + cbase + c) * 8 + b] = v;
    }
    if (w == 3) {
      float v = wave_sum(qq[b]);
      if (lane == 0) part[(pb + 15) * 8 + b] = v;
    }
  }
  if (bt == 0) {
#pragma unroll
    for (int c = 0; c < 4; ++c) {
      float v = wave_sum(kkv[c]);
      if (lane == 0 && c < ccnt) kkpart[lc * 16 + cbase + c] = v;
    }
  }
}

// Final reduce: 1 block, thread b handles query b.
__global__ __launch_bounds__(256) void retrieve_reduce(
    const float* __restrict__ part, const float* __restrict__ kkpart,
    float* __restrict__ out) {
  __shared__ float kn[NCLS];
  const int t = threadIdx.x;
  if (t < NCLS) {
    float s = 0.f;
    for (int lc = 0; lc < NCHUNK; ++lc) s += kkpart[lc * 16 + t];
    kn[t] = s;
  }
  __syncthreads();
  const int bt = t >> 3, bi = t & 7;
  float qq = 0.f;
  for (int lc = 0; lc < NCHUNK; ++lc)
    qq += part[((size_t)(lc * NBT + bt) * 16 + 15) * 8 + bi];
  float dmin = INFINITY;
  int didx = 0;
  for (int c = 0; c < NCLS; ++c) {
    float dot = 0.f;
    for (int lc = 0; lc < NCHUNK; ++lc)
      dot += part[((size_t)(lc * NBT + bt) * 16 + c) * 8 + bi];
    float d2 = qq + kn[c] - 2.f * dot;
    float d = sqrtf(fmaxf(d2, 1e-12f));
    if (d < dmin) { dmin = d; didx = c; }
  }
  out[t] = dmin;
  out[256 + t] = (float)didx;
}

// Persistent cooperative FPS kernel. Global protocol byte-identical to r11
// (parity-double-buffered agent-scope words -> hub gather -> x8 replicated
// result). NEW: zero __syncthreads in the step loop — all in-block
// coordination is step-tagged LDS words (payload-in-word, same proof shape
// as the global protocol; an LDS hop is ~50cyc vs ~0.7us fabric):
//   - waves write wkey[par][w] tagged; wave0's lanes0-15 poll them
//     (divergent-exec loop = wait-for-all), butterfly, post.
//   - result broadcast by tagged lres[par]; all threads spin on it
//     (same-address LDS read = broadcast) and resume compute immediately.
// Slot-reuse safety (inductive, as r5/r11): any slot written at step s+2
// requires its writer consumed lres@s+1, which happens-after every read of
// that slot@s. Compute arithmetic FROZEN (absmax 0.0); reduces exact u64.
__global__ __launch_bounds__(1024, 4) void fps_kernel(
    const float* __restrict__ emb,
    u64* __restrict__ words,                  // [2*NBLK], memset 0 per launch
    u64* __restrict__ res8,                   // [8][RSTRIDE], memset 0
    float* __restrict__ out_samples) {
  extern __shared__ float e_lds[];            // [PPB*DIM] = 150528 B
  const int tid = threadIdx.x;
  const int blk = blockIdx.x;
  const int w = tid >> 6, lane = tid & 63;
  const int q4 = lane >> 4;                   // quarter 0..3
  const int r = lane & 15;                    // lane within quarter
  const int pl = w * 4 + q4;                  // local point slot 0..63
  const bool valid = pl < PPB;
  const int p = valid ? pl : 0;               // clamped for addressing

  __shared__ int hist[NSAMP];
  __shared__ u64 wkey[2][16];
  __shared__ u64 swin[2][4];
  __shared__ u64 lres[2];

  // Stage this block's 49 embedding rows into LDS (coalesced).
  {
    const float* src = emb + (size_t)blk * EPB;
    for (int i = tid; i < EPB; i += 1024) e_lds[i] = src[i];
  }
  if (tid == 0) {
    hist[0] = 0;
#pragma unroll
    for (int i = 0; i < 16; ++i) { wkey[0][i] = 0ull; wkey[1][i] = 0ull; }
#pragma unroll
    for (int i = 0; i < 4; ++i) { swin[0][i] = 0ull; swin[1][i] = 0ull; }
    lres[0] = 0ull; lres[1] = 0ull;
  }
  __syncthreads();

  // Squared norm of this lane's point (48 dims per lane, 4-stage reduce).
  const float4* ef = (const float4*)(e_lds + (size_t)p * DIM);
  float sq;
  {
    float ss = 0.f;
#pragma unroll
    for (int jj = 0; jj < 12; ++jj) {
      float4 v = ef[r + jj * 16];
      ss = fmaf(v.x, v.x, ss); ss = fmaf(v.y, v.y, ss);
      ss = fmaf(v.z, v.z, ss); ss = fmaf(v.w, v.w, ss);
    }
#pragma unroll
    for (int m = 1; m < 16; m <<= 1) ss += __shfl_xor(ss, m, 64);
    sq = ss;
  }
  float dist2 = INFINITY;
  int last = 0;

  for (int s = 1; s < NSAMP; ++s) {
    const int par = s & 1;
    const int buf = par * NBLK;

    // Centroid float4s (issued early; L3 latency overlaps the ds_reads).
    const float4* cf = (const float4*)(emb + (size_t)last * DIM);
    float4 cv[12];
#pragma unroll
    for (int jj = 0; jj < 12; ++jj) cv[jj] = cf[r + jj * 16];

    // Per-lane partial dot (48 dims) and |c|^2 partial; 4-stage reduce.
    float a = 0.f, cn = 0.f;
#pragma unroll
    for (int jj = 0; jj < 12; ++jj) {
      float4 e4 = ef[r + jj * 16];
      float4 c4 = cv[jj];
      a = fmaf(e4.x, c4.x, a); a = fmaf(e4.y, c4.y, a);
      a = fmaf(e4.z, c4.z, a); a = fmaf(e4.w, c4.w, a);
      cn = fmaf(c4.x, c4.x, cn); cn = fmaf(c4.y, c4.y, cn);
      cn = fmaf(c4.z, c4.z, cn); cn = fmaf(c4.w, c4.w, cn);
    }
#pragma unroll
    for (int m = 1; m < 16; m <<= 1) {
      a += __shfl_xor(a, m, 64);
      cn += __shfl_xor(cn, m, 64);
    }

    // Running min (squared space) + key; wave max over the 4 quarters.
    u64 key = 0ull;
    if (valid) {
      float d2 = sq - 2.f * a + cn;
      if (d2 < dist2) dist2 = d2;
      key = ((u64)__float_as_uint(dist2) << 32) |
            (u32)(~(u32)(blk * PPB + pl));
    }
#pragma unroll
    for (int m = 16; m < 64; m <<= 1) {
      u64 o = __shfl_xor(key, m, 64);
      if (o > key) key = o;
    }

    // Tagged LDS post of this wave's key (replaces barrier #1).
    if (lane == 0)
      __hip_atomic_store(&wkey[par][w], word_from_key((u64)s, key),
                         __ATOMIC_RELAXED, __HIP_MEMORY_SCOPE_WORKGROUP);

    // Wave 0: gather the 16 wave keys (LDS tag poll), butterfly, post.
    if (w == 0) {
      u64 kw = 0ull;
      if (lane < 16) {
        u64 t64;
        for (;;) {
          t64 = __hip_atomic_load(&wkey[par][lane], __ATOMIC_RELAXED,
                                  __HIP_MEMORY_SCOPE_WORKGROUP);
          if ((t64 >> 48) >= (u64)s) break;
        }
        kw = key_from_word(t64);
      }
#pragma unroll
      for (int m = 1; m < 16; m <<= 1) {
        u64 o = __shfl_xor(kw, m, 64);
        if (o > kw) kw = o;
      }
      if (lane == 0)
        __hip_atomic_store(&words[buf + blk], word_from_key((u64)s, kw),
                           __ATOMIC_RELAXED, __HIP_MEMORY_SCOPE_AGENT);
    }

    if (blk == 0) {
      // Hub gather: waves 0-3 poll the 256 global words, per-wave max into
      // tagged swin; wave 0 reduces the 4, publishes 8 replicas + lres.
      if (tid < NBLK) {
        u64 w64;
        for (;;) {
          w64 = __hip_atomic_load(&words[buf + tid], __ATOMIC_RELAXED,
                                  __HIP_MEMORY_SCOPE_AGENT);
          if ((w64 >> 48) >= (u64)s) break;
        }
        u64 kk = wave_max_u64(key_from_word(w64));
        if (lane == 0)
          __hip_atomic_store(&swin[par][w], word_from_key((u64)s, kk),
                             __ATOMIC_RELAXED, __HIP_MEMORY_SCOPE_WORKGROUP);
      }
      if (w == 0) {
        u64 sw = 0ull;
        if (lane < 4) {
          u64 t64;
          for (;;) {
            t64 = __hip_atomic_load(&swin[par][lane], __ATOMIC_RELAXED,
                                    __HIP_MEMORY_SCOPE_WORKGROUP);
            if ((t64 >> 48) >= (u64)s) break;
          }
          sw = key_from_word(t64);
        }
#pragma unroll
        for (int m = 1; m < 4; m <<= 1) {
          u64 o = __shfl_xor(sw, m, 64);
          if (o > sw) sw = o;
        }
        const u64 fin = __shfl(sw, 0, 64);
        const int widx = (int)(~(u32)(fin & 0xffffffffull));
        const u64 rw = ((u64)s << 32) | (u32)widx;
        if (lane < 8)
          __hip_atomic_store(&res8[(size_t)lane * RSTRIDE], rw,
                             __ATOMIC_RELAXED, __HIP_MEMORY_SCOPE_AGENT);
        if (lane == 0) {
          hist[s] = widx;
          __hip_atomic_store(&lres[par], rw, __ATOMIC_RELAXED,
                             __HIP_MEMORY_SCOPE_WORKGROUP);
        }
      }
    } else {
      // Spoke: wave0 lane0 polls this block's replica (4-deep), relays to
      // the block via tagged lres.
      if (tid == 0) {
        const u64* rp = &res8[(size_t)(blk & 7) * RSTRIDE];
        u64 r0, r1, r2, r3, rr;
        for (;;) {
          r0 = __hip_atomic_load(rp, __ATOMIC_RELAXED,
                                 __HIP_MEMORY_SCOPE_AGENT);
          r1 = __hip_atomic_load(rp, __ATOMIC_RELAXED,
                                 __HIP_MEMORY_SCOPE_AGENT);
          r2 = __hip_atomic_load(rp, __ATOMIC_RELAXED,
                                 __HIP_MEMORY_SCOPE_AGENT);
          r3 = __hip_atomic_load(rp, __ATOMIC_RELAXED,
                                 __HIP_MEMORY_SCOPE_AGENT);
          if ((r3 >> 32) >= (u64)s) { rr = r3; break; }
          if ((r2 >> 32) >= (u64)s) { rr = r2; break; }
          if ((r1 >> 32) >= (u64)s) { rr = r1; break; }
          if ((r0 >> 32) >= (u64)s) { rr = r0; break; }
        }
        hist[s] = (int)(u32)(rr & 0xffffffffull);
        __hip_atomic_store(&lres[par], rr, __ATOMIC_RELAXED,
                           __HIP_MEMORY_SCOPE_WORKGROUP);
      }
    }

    // Everyone: spin on the tagged local result word (replaces barrier #2;
    // same-address LDS reads broadcast). Resume compute immediately.
    u64 lr;
    for (;;) {
      lr = __hip_atomic_load(&lres[par], __ATOMIC_RELAXED,
                             __HIP_MEMORY_SCOPE_WORKGROUP);
      if ((lr >> 32) >= (u64)s) break;
    }
    last = (int)(u32)(lr & 0xffffffffull);
  }

  __syncthreads();   // hist[] fully written before gather
  // Gather samples: block blk copies row hist[blk] (no cross-block dep).
  if (blk < NSAMP) {
    const int idx = hist[blk];
    const float4* src = (const float4*)(emb + (size_t)idx * DIM);
    float4* dst = (float4*)(out_samples + (size_t)blk * DIM);
    if (tid < DIM / 4) dst[tid] = src[tid];
  }
}

extern "C" void kernel_launch(void* const* d_in, const int* in_sizes, int n_in,
                              void* d_out, int out_size, void* d_ws, size_t ws_size,
                              hipStream_t stream) {
  const float* q   = (const float*)d_in[0];   // [256, 196, 768]
  const float* k   = (const float*)d_in[1];   // [15, 196, 768]
  const float* emb = (const float*)d_in[2];   // [12544, 768]
  float* out = (float*)d_out;                 // [256 dist | 256 idx | 196*768 samples]

  u64* words = (u64*)d_ws;                          // [512] = 4096 B
  u64* res8  = (u64*)((char*)d_ws + 4096);          // [8][16] = 1024 B
  float* part   = (float*)((char*)d_ws + 8192);     // 7*32*16*8 = 28672 f
  float* kkpart = part + 28672;                     // 112 f

  // Reset sync state (stale tags from prior replays must not alias).
  hipMemsetAsync(d_ws, 0, 8192, stream);

  hipLaunchKernelGGL(retrieve_partial, dim3(NBT, NCHUNK), dim3(256), 0, stream,
                     q, k, part, kkpart);
  hipLaunchKernelGGL(retrieve_reduce, dim3(1), dim3(256), 0, stream,
                     part, kkpart, out);

  hipFuncSetAttribute((const void*)fps_kernel,
                      hipFuncAttributeMaxDynamicSharedMemorySize,
                      EPB * sizeof(float));

  float* samples = out + 512;
  void* args[] = {(void*)&emb, (void*)&words, (void*)&res8, (void*)&samples};
  hipLaunchCooperativeKernel((void*)fps_kernel, dim3(NBLK), dim3(1024), args,
                             EPB * sizeof(float), stream);
}

// Round 13
// 870.240 us; speedup vs baseline: 1.0445x; 1.0445x over previous
//
#include <hip/hip_runtime.h>
#include <math.h>

typedef unsigned long long u64;
typedef unsigned int u32;

// ---------------- retrieve_key: [256] queries vs [15] keys over L=150528 ----
#define L_TOT  150528
#define ROW4   37632      // L_TOT/4 float4 per row
#define NCHUNK 7
#define CH4    5376       // ROW4/NCHUNK
#define R_ITERS 84        // CH4/64
#define NBT    32         // b-tiles of 8
#define BTILE  8
#define NCLS   15

// ---------------- FPS ------------------------------------------------------
#define N_E    12544
#define DIM    768
#define NBLK   256
#define PPB    49         // points per block (256*49 = 12544, exact)
#define NSAMP  196
#define EPB    (PPB*DIM)  // 37632 floats = 150528 B in LDS
#define RSTRIDE 16        // u64 stride between result replicas (128 B)

__device__ __forceinline__ float wave_sum(float v) {
#pragma unroll
  for (int m = 1; m < 64; m <<= 1) v += __shfl_xor(v, m, 64);
  return v;
}

__device__ __forceinline__ u64 wave_max_u64(u64 v) {
#pragma unroll
  for (int m = 1; m < 64; m <<= 1) {
    u64 o = __shfl_xor(v, m, 64);
    if (o > v) v = o;
  }
  return v;
}

// Partial dot products: grid (32 b-tiles, 7 L-chunks), block 256.
__global__ __launch_bounds__(256) void retrieve_partial(
    const float* __restrict__ q, const float* __restrict__ k,
    float* __restrict__ part, float* __restrict__ kkpart) {
  const int bt = blockIdx.x;     // 0..31
  const int lc = blockIdx.y;     // 0..6
  const int tid = threadIdx.x;
  const int w = tid >> 6, lane = tid & 63;
  const int cbase = w * 4;
  const int ccnt = (w == 3) ? 3 : 4;
  const float4* qf = (const float4*)q;
  const float4* kf = (const float4*)k;
  const int fbase = lc * CH4 + lane;

  float acc[BTILE][4];
  float qq[BTILE];
  float kkv[4];
#pragma unroll
  for (int b = 0; b < BTILE; ++b) {
    qq[b] = 0.f;
#pragma unroll
    for (int c = 0; c < 4; ++c) acc[b][c] = 0.f;
  }
#pragma unroll
  for (int c = 0; c < 4; ++c) kkv[c] = 0.f;

  for (int it = 0; it < R_ITERS; ++it) {
    const int f = fbase + it * 64;
    float4 kv[4];
#pragma unroll
    for (int c = 0; c < 4; ++c)
      if (c < ccnt) kv[c] = kf[(size_t)(cbase + c) * ROW4 + f];
    if (bt == 0) {
#pragma unroll
      for (int c = 0; c < 4; ++c)
        if (c < ccnt)
          kkv[c] += kv[c].x*kv[c].x + kv[c].y*kv[c].y + kv[c].z*kv[c].z + kv[c].w*kv[c].w;
    }
#pragma unroll
    for (int b = 0; b < BTILE; ++b) {
      float4 qv = qf[(size_t)(bt * BTILE + b) * ROW4 + f];
#pragma unroll
      for (int c = 0; c < 4; ++c)
        if (c < ccnt)
          acc[b][c] += qv.x*kv[c].x + qv.y*kv[c].y + qv.z*kv[c].z + qv.w*kv[c].w;
      if (w == 3)
        qq[b] += qv.x*qv.x + qv.y*qv.y + qv.z*qv.z + qv.w*qv.w;
    }
  }

  const size_t pb = (size_t)(lc * NBT + bt) * 16;
#pragma unroll
  for (int b = 0; b < BTILE; ++b) {
#pragma unroll
    for (int c = 0; c < 4; ++c) {
      float v = wave_sum(acc[b][c]);
      if (lane == 0 && c < ccnt) part[(pb + cbase + c) * 8 + b] = v;
    }
    if (w == 3) {
      float v = wave_sum(qq[b]);
      if (lane == 0) part[(pb + 15) * 8 + b] = v;
    }
  }
  if (bt == 0) {
#pragma unroll
    for (int c = 0; c < 4; ++c) {
      float v = wave_sum(kkv[c]);
      if (lane == 0 && c < ccnt) kkpart[lc * 16 + cbase + c] = v;
    }
  }
}

// Final reduce: 1 block, thread b handles query b.
__global__ __launch_bounds__(256) void retrieve_reduce(
    const float* __restrict__ part, const float* __restrict__ kkpart,
    float* __restrict__ out) {
  __shared__ float kn[NCLS];
  const int t = threadIdx.x;
  if (t < NCLS) {
    float s = 0.f;
    for (int lc = 0; lc < NCHUNK; ++lc) s += kkpart[lc * 16 + t];
    kn[t] = s;
  }
  __syncthreads();
  const int bt = t >> 3, bi = t & 7;
  float qq = 0.f;
  for (int lc = 0; lc < NCHUNK; ++lc)
    qq += part[((size_t)(lc * NBT + bt) * 16 + 15) * 8 + bi];
  float dmin = INFINITY;
  int didx = 0;
  for (int c = 0; c < NCLS; ++c) {
    float dot = 0.f;
    for (int lc = 0; lc < NCHUNK; ++lc)
      dot += part[((size_t)(lc * NBT + bt) * 16 + c) * 8 + bi];
    float d2 = qq + kn[c] - 2.f * dot;
    float d = sqrtf(fmaxf(d2, 1e-12f));
    if (d < dmin) { dmin = d; didx = c; }
  }
  out[t] = dmin;
  out[256 + t] = (float)didx;
}

// Persistent cooperative FPS kernel — round-11 structure (best verified:
// headline 874us, fps 776us, absmax 0.0). Hub gather with parity
// double-buffered agent-scope posts; result replicated x8 on separate
// 128B lines (spoke blk polls replica blk&7, ~32 pollers/line).
// Compute arithmetic FROZEN (absmax 0.0 vs reference).
// This structure is at its measured floor: r8 probes put the 2-fabric-hop
// all-reduce at ~2.1us/step; every structural deviation tried (a2a r6,
// wave-poll r7, XCD 2-level r9, LDS-atomic r10, tag-spin r12) regressed
// or deadlocked.
__global__ __launch_bounds__(1024, 4) void fps_kernel(
    const float* __restrict__ emb,
    u64* __restrict__ words,                  // [2*NBLK], memset 0 per launch
    u64* __restrict__ res8,                   // [8][RSTRIDE], memset 0
    float* __restrict__ out_samples) {
  extern __shared__ float e_lds[];            // [PPB*DIM] = 150528 B
  const int tid = threadIdx.x;
  const int blk = blockIdx.x;
  const int w = tid >> 6, lane = tid & 63;
  const int q4 = lane >> 4;                   // quarter 0..3
  const int r = lane & 15;                    // lane within quarter
  const int pl = w * 4 + q4;                  // local point slot 0..63
  const bool valid = pl < PPB;
  const int p = valid ? pl : 0;               // clamped for addressing

  __shared__ int hist[NSAMP];
  __shared__ u64 wkey[16];
  __shared__ u64 swin[4];

  // Stage this block's 49 embedding rows into LDS (coalesced).
  {
    const float* src = emb + (size_t)blk * EPB;
    for (int i = tid; i < EPB; i += 1024) e_lds[i] = src[i];
  }
  __syncthreads();

  // Squared norm of this lane's point (48 dims per lane, 4-stage reduce).
  const float4* ef = (const float4*)(e_lds + (size_t)p * DIM);
  float sq;
  {
    float ss = 0.f;
#pragma unroll
    for (int jj = 0; jj < 12; ++jj) {
      float4 v = ef[r + jj * 16];
      ss = fmaf(v.x, v.x, ss); ss = fmaf(v.y, v.y, ss);
      ss = fmaf(v.z, v.z, ss); ss = fmaf(v.w, v.w, ss);
    }
#pragma unroll
    for (int m = 1; m < 16; m <<= 1) ss += __shfl_xor(ss, m, 64);
    sq = ss;
  }
  float dist2 = INFINITY;
  int last = 0;
  if (tid == 0) hist[0] = 0;
  __syncthreads();

  for (int s = 1; s < NSAMP; ++s) {
    const int buf = (s & 1) * NBLK;

    // Centroid float4s (issued early; L3 latency overlaps the ds_reads).
    const float4* cf = (const float4*)(emb + (size_t)last * DIM);
    float4 cv[12];
#pragma unroll
    for (int jj = 0; jj < 12; ++jj) cv[jj] = cf[r + jj * 16];

    // Per-lane partial dot (48 dims) and |c|^2 partial; 4-stage reduce.
    float a = 0.f, cn = 0.f;
#pragma unroll
    for (int jj = 0; jj < 12; ++jj) {
      float4 e4 = ef[r + jj * 16];
      float4 c4 = cv[jj];
      a = fmaf(e4.x, c4.x, a); a = fmaf(e4.y, c4.y, a);
      a = fmaf(e4.z, c4.z, a); a = fmaf(e4.w, c4.w, a);
      cn = fmaf(c4.x, c4.x, cn); cn = fmaf(c4.y, c4.y, cn);
      cn = fmaf(c4.z, c4.z, cn); cn = fmaf(c4.w, c4.w, cn);
    }
#pragma unroll
    for (int m = 1; m < 16; m <<= 1) {
      a += __shfl_xor(a, m, 64);
      cn += __shfl_xor(cn, m, 64);
    }

    // Running min (squared space) + key; wave max over the 4 quarters.
    u64 key = 0ull;
    if (valid) {
      float d2 = sq - 2.f * a + cn;
      if (d2 < dist2) dist2 = d2;
      key = ((u64)__float_as_uint(dist2) << 32) |
            (u32)(~(u32)(blk * PPB + pl));
    }
#pragma unroll
    for (int m = 16; m < 64; m <<= 1) {
      u64 o = __shfl_xor(key, m, 64);
      if (o > key) key = o;
    }
    if (lane == 0) wkey[w] = key;
    __syncthreads();

    // Phase 1: wave-0 16-lane butterfly block-reduce, lane 0 posts.
    if (w == 0) {
      u64 k = wkey[lane & 15];
#pragma unroll
      for (int m = 1; m < 16; m <<= 1) {
        u64 o = __shfl_xor(k, m, 64);
        if (o > k) k = o;
      }
      if (lane == 0) {
        const u32 bidx = ~(u32)(k & 0xffffffffull);   // global point idx
        const u32 bdist = (u32)(k >> 32);
        const u64 word = ((u64)s << 48) | ((u64)bdist << 16) | (u64)bidx;
        __hip_atomic_store(&words[buf + blk], word, __ATOMIC_RELAXED,
                           __HIP_MEMORY_SCOPE_AGENT);
      }
    }

    if (blk == 0) {
      // Phase 2 (hub): poll all 256 words, reduce, publish 8 result replicas.
      if (tid < NBLK) {
        u64 w64;
        for (;;) {
          w64 = __hip_atomic_load(&words[buf + tid], __ATOMIC_RELAXED,
                                  __HIP_MEMORY_SCOPE_AGENT);
          if ((w64 >> 48) >= (u64)s) break;
        }
        u64 kk = (((w64 >> 16) & 0xffffffffull) << 32) |
                 (u64)(u32)(~(u32)(w64 & 0xffffull));
        kk = wave_max_u64(kk);
        if (lane == 0) swin[w] = kk;
      }
      __syncthreads();
      if (tid == 0) {
        u64 m = swin[0];
#pragma unroll
        for (int qi = 1; qi < 4; ++qi) if (swin[qi] > m) m = swin[qi];
        const int widx = (int)(~(u32)(m & 0xffffffffull));
        hist[s] = widx;
        const u64 rw = ((u64)s << 32) | (u32)widx;
#pragma unroll
        for (int c = 0; c < 8; ++c)
          __hip_atomic_store(&res8[(size_t)c * RSTRIDE], rw,
                             __ATOMIC_RELAXED, __HIP_MEMORY_SCOPE_AGENT);
      }
      __syncthreads();
    } else {
      // Phase 3: one thread polls this block's result replica line (4
      // in-flight loads per round to cut detect granularity below one RT).
      if (tid == 0) {
        const u64* rp = &res8[(size_t)(blk & 7) * RSTRIDE];
        u64 r0, r1, r2, r3, rr;
        for (;;) {
          r0 = __hip_atomic_load(rp, __ATOMIC_RELAXED,
                                 __HIP_MEMORY_SCOPE_AGENT);
          r1 = __hip_atomic_load(rp, __ATOMIC_RELAXED,
                                 __HIP_MEMORY_SCOPE_AGENT);
          r2 = __hip_atomic_load(rp, __ATOMIC_RELAXED,
                                 __HIP_MEMORY_SCOPE_AGENT);
          r3 = __hip_atomic_load(rp, __ATOMIC_RELAXED,
                                 __HIP_MEMORY_SCOPE_AGENT);
          if ((r3 >> 32) >= (u64)s) { rr = r3; break; }
          if ((r2 >> 32) >= (u64)s) { rr = r2; break; }
          if ((r1 >> 32) >= (u64)s) { rr = r1; break; }
          if ((r0 >> 32) >= (u64)s) { rr = r0; break; }
        }
        hist[s] = (int)(u32)(rr & 0xffffffffull);
      }
      __syncthreads();
    }
    last = hist[s];
  }

  // Gather samples: block blk copies row hist[blk] (no cross-block dep).
  if (blk < NSAMP) {
    const int idx = hist[blk];
    const float4* src = (const float4*)(emb + (size_t)idx * DIM);
    float4* dst = (float4*)(out_samples + (size_t)blk * DIM);
    if (tid < DIM / 4) dst[tid] = src[tid];
  }
}

extern "C" void kernel_launch(void* const* d_in, const int* in_sizes, int n_in,
                              void* d_out, int out_size, void* d_ws, size_t ws_size,
                              hipStream_t stream) {
  const float* q   = (const float*)d_in[0];   // [256, 196, 768]
  const float* k   = (const float*)d_in[1];   // [15, 196, 768]
  const float* emb = (const float*)d_in[2];   // [12544, 768]
  float* out = (float*)d_out;                 // [256 dist | 256 idx | 196*768 samples]

  u64* words = (u64*)d_ws;                          // [512] = 4096 B
  u64* res8  = (u64*)((char*)d_ws + 4096);          // [8][16] = 1024 B
  float* part   = (float*)((char*)d_ws + 8192);     // 7*32*16*8 = 28672 f
  float* kkpart = part + 28672;                     // 112 f

  // Reset sync state (stale tags from prior replays must not alias).
  hipMemsetAsync(d_ws, 0, 8192, stream);

  hipLaunchKernelGGL(retrieve_partial, dim3(NBT, NCHUNK), dim3(256), 0, stream,
                     q, k, part, kkpart);
  hipLaunchKernelGGL(retrieve_reduce, dim3(1), dim3(256), 0, stream,
                     part, kkpart, out);

  hipFuncSetAttribute((const void*)fps_kernel,
                      hipFuncAttributeMaxDynamicSharedMemorySize,
                      EPB * sizeof(float));

  float* samples = out + 512;
  void* args[] = {(void*)&emb, (void*)&words, (void*)&res8, (void*)&samples};
  hipLaunchCooperativeKernel((void*)fps_kernel, dim3(NBLK), dim3(1024), args,
                             EPB * sizeof(float), stream);
}